// Round 9
// baseline (338.432 us; speedup 1.0000x reference)
//
#include <hip/hip_runtime.h>

#define B_ 4
#define S_ 2048
#define E_ 512
#define H_ 8
#define HD_ 64

typedef float f32x4 __attribute__((ext_vector_type(4)));
typedef __bf16 bf16x8 __attribute__((ext_vector_type(8)));

#define MFMA16(a, b, c) __builtin_amdgcn_mfma_f32_16x16x32_bf16((a), (b), (c), 0, 0, 0)

__device__ __forceinline__ unsigned f2bfu(float f) {
  union { float f; unsigned u; } x; x.f = f;
  return (x.u + 0x8000u) >> 16;
}
__device__ __forceinline__ unsigned pk2bf(float lo, float hi) {
  union { float f; unsigned u; } a, b; a.f = lo; b.f = hi;
  return ((b.u + 0x8000u) & 0xFFFF0000u) | ((a.u + 0x8000u) >> 16);
}
// 4x f32 -> 4x bf16 (RNE) packed in uint2; compiler emits v_cvt_pk_bf16_f32.
__device__ __forceinline__ uint2 pk4bf(float a, float b, float c, float d) {
  union { __bf16 h[4]; uint2 q; } u;
  u.h[0] = (__bf16)a; u.h[1] = (__bf16)b; u.h[2] = (__bf16)c; u.h[3] = (__bf16)d;
  return u.q;
}
__device__ __forceinline__ float bf2f(unsigned short s) {
  union { unsigned u; float f; } x; x.u = ((unsigned)s) << 16;
  return x.f;
}
__device__ __forceinline__ float fast_exp2(float x) {
  float r;
  __asm__("v_exp_f32 %0, %1" : "=v"(r) : "v"(x));
  return r;
}
// async global->LDS, 16B per lane. LDS dest = wave-uniform base + lane*16.
__device__ __forceinline__ void gload_lds16(const unsigned short* g, unsigned short* l) {
  __builtin_amdgcn_global_load_lds(
      (const __attribute__((address_space(1))) unsigned int*)g,
      (__attribute__((address_space(3))) unsigned int*)l, 16, 0, 0);
}

// ---------------------------------------------------------------------------
// Fused input conversion. blocks 0..2047: x -> xb (bf16).
// blocks 2048..2431: W (128/matrix); 2432..2495: Er (d-permuted);
// 2496: zero row + zero the 128 LN completion counters (R15).
// ---------------------------------------------------------------------------
__global__ __launch_bounds__(256) void conv_all(
    const float* __restrict__ x, const float* __restrict__ Wq,
    const float* __restrict__ Wk, const float* __restrict__ Wv,
    const float* __restrict__ Er, unsigned short* __restrict__ xb,
    unsigned short* __restrict__ wb, unsigned short* __restrict__ erb,
    int* __restrict__ cnt)
{
  const int bid = blockIdx.x, tid = threadIdx.x;
  if (bid < 2048) {
    size_t i = ((size_t)bid * 256 + tid) * 8;
    float4 f0 = *(const float4*)&x[i];
    float4 f1 = *(const float4*)&x[i + 4];
    uint4 o;
    o.x = pk2bf(f0.x, f0.y); o.y = pk2bf(f0.z, f0.w);
    o.z = pk2bf(f1.x, f1.y); o.w = pk2bf(f1.z, f1.w);
    *(uint4*)&xb[i] = o;
  } else if (bid < 2432) {
    int wz = bid - 2048;
    int z = wz >> 7, mi = wz & 127;
    const float* src = (z == 0) ? Wq : (z == 1) ? Wk : Wv;
    size_t off = (size_t)mi * 2048 + tid * 8;
    float4 f0 = *(const float4*)&src[off];
    float4 f1 = *(const float4*)&src[off + 4];
    uint4 o;
    o.x = pk2bf(f0.x, f0.y); o.y = pk2bf(f0.z, f0.w);
    o.z = pk2bf(f1.x, f1.y); o.w = pk2bf(f1.z, f1.w);
    *(uint4*)&wb[(size_t)z * 262144 + off] = o;
  } else if (bid < 2496) {
    size_t off = (size_t)(bid - 2432) * 2048 + tid * 8;
    int row = (int)(off >> 6), d0 = (int)(off & 63);
    float4 f0 = *(const float4*)&Er[off];
    float4 f1 = *(const float4*)&Er[off + 4];
    float vals[8] = {f0.x, f0.y, f0.z, f0.w, f1.x, f1.y, f1.z, f1.w};
#pragma unroll
    for (int j = 0; j < 8; ++j) {
      int d = d0 + j;
      int dp = (d & 15) * 4 + (d >> 4);
      erb[(size_t)row * 64 + dp] = (unsigned short)f2bfu(vals[j]);
    }
  } else {
    if (tid < 8) *(uint4*)&erb[2048 * 64 + tid * 8] = make_uint4(0, 0, 0, 0);
    if (tid >= 128 && tid < 256) cnt[tid - 128] = 0;
  }
}

// ---------------------------------------------------------------------------
// QKV projection, pure-bf16 MFMA with global_load_lds staging.
// z in {0,1}: out[z] = bf16(xb @ wb[z]^T) to qkvb, d-axis permuted within
//   64-blocks (d' = (d&15)*4 + d>>4), Q pre-scaled by 512^-0.5 * log2(e).
// z == 2: fused V transpose epilogue writes vtb directly in attn's
//   [d][t-perm] layout (t(p) = (p&32)+((p>>2)&1)*16+((p>>3)&3)*4+(p&3)).
// M=8192,N=512,K=512. grid (64,4,3), 256 thr.
// ---------------------------------------------------------------------------
__global__ __launch_bounds__(256) void qkv_gemm_mfma(
    const unsigned short* __restrict__ xb, const unsigned short* __restrict__ wb,
    unsigned short* __restrict__ qkvb, unsigned short* __restrict__ vtb)
{
  const int z = blockIdx.z;
  const unsigned short* W = wb + (size_t)z * 262144;
  const int m0 = blockIdx.x * 128, n0 = blockIdx.y * 128;

  // 34816B: As (16KB) | Bs (16KB) during K-loop; Tt 4x64x68 in epilogue (z==2)
  __shared__ __align__(16) unsigned short SMEM[17408];
  unsigned short* As = SMEM;
  unsigned short* Bs = SMEM + 8192;

  const int tid = threadIdx.x;
  const int w = tid >> 6, l = tid & 63, lm = l & 15, lq = l >> 4;
  const int wm = w & 1, wn = w >> 1;

  union u4bf { uint4 u; bf16x8 v; };
  f32x4 acc[4][4];
#pragma unroll
  for (int a = 0; a < 4; ++a)
#pragma unroll
    for (int b = 0; b < 4; ++b) acc[a][b] = (f32x4){0.f, 0.f, 0.f, 0.f};

  for (int k0 = 0; k0 < 512; k0 += 64) {
    const unsigned short* xa = xb + (size_t)m0 * 512 + k0;
    const unsigned short* wz = W + (size_t)n0 * 512 + k0;
    __syncthreads();
#pragma unroll
    for (int rr = 0; rr < 4; ++rr) {
      int cb = rr * 256 + w * 64;
      int s = cb + l;
      int row = s >> 3, c = (s & 7) ^ (row & 7);
      gload_lds16(&xa[(size_t)row * 512 + c * 8], &As[cb * 8]);
      gload_lds16(&wz[(size_t)row * 512 + c * 8], &Bs[cb * 8]);
    }
    __syncthreads();
#pragma unroll
    for (int ka = 0; ka < 2; ++ka) {
      u4bf af[4];
#pragma unroll
      for (int mt = 0; mt < 4; ++mt) {
        int row = wm * 64 + mt * 16 + lm;
        af[mt].u = *(const uint4*)&As[row * 64 + (((ka * 4 + lq) ^ (row & 7)) * 8)];
      }
#pragma unroll
      for (int nt = 0; nt < 4; ++nt) {
        int row = wn * 64 + nt * 16 + lm;
        u4bf bfv;
        bfv.u = *(const uint4*)&Bs[row * 64 + (((ka * 4 + lq) ^ (row & 7)) * 8)];
#pragma unroll
        for (int mt = 0; mt < 4; ++mt) acc[mt][nt] = MFMA16(af[mt].v, bfv.v, acc[mt][nt]);
      }
    }
  }

  if (z != 2) {
    const float m = (z == 0) ? 0.06376695f : 1.0f;  // 512^-0.5 * log2(e) for Q
    unsigned short* out = qkvb + (size_t)z * (8192u * 512u);
#pragma unroll
    for (int mt = 0; mt < 4; ++mt)
#pragma unroll
      for (int reg = 0; reg < 4; ++reg) {
        int row = m0 + wm * 64 + mt * 16 + lq * 4 + reg;
        uint2 v = make_uint2(
            pk2bf(acc[mt][0][reg] * m, acc[mt][1][reg] * m),
            pk2bf(acc[mt][2][reg] * m, acc[mt][3][reg] * m));
        *(uint2*)&out[(size_t)row * 512 + n0 + wn * 64 + lm * 4] = v;
      }
  } else {
    // ---- fused V transpose: wave (wm,wn) owns the 64t x 64d subtile ----
    __syncthreads();  // all waves done with As/Bs before aliasing
    unsigned short* R = SMEM + w * 4352;  // 64 x 68 wave-private
#pragma unroll
    for (int mt = 0; mt < 4; ++mt)
#pragma unroll
      for (int nt = 0; nt < 4; ++nt)
#pragma unroll
        for (int reg = 0; reg < 4; ++reg)
          R[(mt * 16 + lq * 4 + reg) * 68 + nt * 16 + lm] =
              (unsigned short)f2bfu(acc[mt][nt][reg]);
    __asm__ __volatile__("" ::: "memory");  // same-wave DS RAW (in-order pipe)
    const int sg0 = m0 + wm * 64;           // global s of this chunk
    const int bb = sg0 >> 11, sl = sg0 & 2047;
    const int db64 = blockIdx.y * 2 + wn;   // 64-wide d block index
#pragma unroll
    for (int it = 0; it < 8; ++it) {
      int j = it * 64 + l;
      int dp = j >> 3, s8 = (j & 7) * 8;
      union { unsigned short u[8]; uint4 q; } tmp;
#pragma unroll
      for (int jj = 0; jj < 8; ++jj) {
        int p = s8 + jj;
        int ts = (p & 32) + (((p >> 2) & 1) << 4) + (((p >> 3) & 3) << 2) + (p & 3);
        tmp.u[jj] = R[ts * 68 + dp];
      }
      *(uint4*)&vtb[((size_t)(bb * 512) + db64 * 64 + dp) * 2048 + sl + s8] = tmp.q;
    }
  }
}

// ---------------------------------------------------------------------------
// Fused attention — R15: attn body reverted to R13 exactly (R14's address-
// free gather cut VALU 58->36% but its divergent rslab write path cost
// +27us in the lockstep schedule — full revert). NEW: LayerNorm fused via
// last-block completion. The 8 blocks (b,qp,h=0..7) produce the complete
// 64x512 rows; each finisher does threadfence (release) + atomicAdd on
// cnt[b*32+qp]; the 8th does threadfence (acquire/inv) and LNs its 64 rows
// (1 row/wave/pass, 16 rows/wave, gamma/beta hoisted). Deletes the ln
// dispatch; LN work overlaps still-running attn blocks.
// Kept: swapped QK, reg-direct PV, XCD remap, setprio, 2 barriers/iter,
// Rx[slot][isel] stride 68. grid (32,32), 256 thr, 4 blocks/CU.
// ---------------------------------------------------------------------------
__global__ __launch_bounds__(256, 4) void attn_mfma(
    const unsigned short* __restrict__ qw, const unsigned short* __restrict__ kw,
    const unsigned short* __restrict__ vt, const unsigned short* __restrict__ erb,
    float* __restrict__ out, int* __restrict__ cnt,
    const float* __restrict__ gamma, const float* __restrict__ beta)
{
  // ---- XCD-aware bijective remap (hw round-robins linear id % 8) ----
  const int Lf = blockIdx.y * 32 + blockIdx.x;
  const int nf = (Lf & 7) * 128 + (Lf >> 3);
  const int qp = nf & 31, bh = nf >> 5;
  const int b = bh >> 3, h = bh & 7;
  const int i0 = qp * 64;

  __shared__ __align__(16) unsigned short Ks[64 * 64];   // [t][d'] swizzled
  __shared__ __align__(16) unsigned short VTs[64 * 64];  // [d][t-perm] swizzled
  __shared__ __align__(16) unsigned short Rx[128 * 68];  // [slot][isel]
  __shared__ int isLast;

  const int tid = threadIdx.x;
  const int w = tid >> 6, l = tid & 63, lm = l & 15, lq = l >> 4;

  const unsigned short* qbase = qw + ((size_t)(b * 2048)) * 512 + h * 64;
  const unsigned short* kbase = kw + ((size_t)(b * 2048)) * 512 + h * 64;
  const unsigned short* vtb = vt + ((size_t)(b * 512 + h * 64)) * 2048;

  union u4bf { uint4 u; bf16x8 v; };

  u4bf ones;
  ones.u = make_uint4(0x3F803F80u, 0x3F803F80u, 0x3F803F80u, 0x3F803F80u);

  // ---- loop-invariant constants ----
  const int ko0 = (lq ^ (lm & 7)) * 8;        // swizzled frag offset, ka=0
  const int ko1 = ((4 + lq) ^ (lm & 7)) * 8;  // ka=1
  const int cnn = 63 + lq * 4 - (w * 16 + lm);  // ai = dbase + cnn + nt*16 + reg
  const int iselb = w * 16 + lm;                // gather column base (own i)
  int il_[4];
#pragma unroll
  for (int reg = 0; reg < 4; ++reg) il_[reg] = w * 16 + lq * 4 + reg;

  // ---- wave's own Q fragment (B-operand of swapped QK) ----
  u4bf aqw[2];
  {
    int gi = i0 + w * 16 + lm;
    aqw[0].u = *(const uint4*)&qbase[(size_t)gi * 512 + lq * 8];
    aqw[1].u = *(const uint4*)&qbase[(size_t)gi * 512 + 32 + lq * 8];
  }
  // ---- Q-ext fragments for rslab (rows rt*16+lm; >64 or OOB -> 0),
  //      constant-indexed ONLY (R2 lesson) ----
  u4bf aq[5][2];
#pragma unroll
  for (int rt = 0; rt < 5; ++rt) {
    int row = rt * 16 + lm, gi = i0 + row;
#pragma unroll
    for (int ka = 0; ka < 2; ++ka) {
      if (row <= 64 && gi < 2048)
        aq[rt][ka].u = *(const uint4*)&qbase[(size_t)gi * 512 + ka * 32 + lq * 8];
      else
        aq[rt][ka].u = make_uint4(0, 0, 0, 0);
    }
  }

  // 4 waves stage a 64x64 tile: two gload_lds16 per wave.
  auto stageTile = [&](const unsigned short* srcBase, size_t srcStride,
                       unsigned short* dst) {
#pragma unroll
    for (int rr = 0; rr < 2; ++rr) {
      int cb = rr * 256 + w * 64;
      int s = cb + l;
      int row = s >> 3, c = (s & 7) ^ (row & 7);
      gload_lds16(&srcBase[(size_t)row * srcStride + c * 8], &dst[cb * 8]);
    }
  };
  auto loadBe = [&](int A0, u4bf& be0, u4bf& be1) {
    int ai = A0 + w * 16 + lm;
    int g = (ai < 64) ? (1984 + ai) : (ai == 64 ? 2048 : ai - 65);
    const unsigned short* ep = &erb[(size_t)g * 64];
    be0.u = *(const uint4*)&ep[lq * 8];
    be1.u = *(const uint4*)&ep[32 + lq * 8];
  };
  auto rslabCompute = [&](int A0, u4bf be0, u4bf be1) {
    f32x4 rc[5];
#pragma unroll
    for (int rt = 0; rt < 5; ++rt) rc[rt] = (f32x4){0.f, 0.f, 0.f, 0.f};
    rc[0] = MFMA16(aq[0][0].v, be0.v, rc[0]);
    rc[0] = MFMA16(aq[0][1].v, be1.v, rc[0]);
    rc[1] = MFMA16(aq[1][0].v, be0.v, rc[1]);
    rc[1] = MFMA16(aq[1][1].v, be1.v, rc[1]);
    rc[2] = MFMA16(aq[2][0].v, be0.v, rc[2]);
    rc[2] = MFMA16(aq[2][1].v, be1.v, rc[2]);
    rc[3] = MFMA16(aq[3][0].v, be0.v, rc[3]);
    rc[3] = MFMA16(aq[3][1].v, be1.v, rc[3]);
    rc[4] = MFMA16(aq[4][0].v, be0.v, rc[4]);
    rc[4] = MFMA16(aq[4][1].v, be1.v, rc[4]);
    int slot = (A0 + w * 16 + lm) & 127;
    unsigned short* rp = &Rx[slot * 68 + lq * 4];
    *(uint2*)&rp[0]  = pk4bf(rc[0][0], rc[0][1], rc[0][2], rc[0][3]);
    *(uint2*)&rp[16] = pk4bf(rc[1][0], rc[1][1], rc[1][2], rc[1][3]);
    *(uint2*)&rp[32] = pk4bf(rc[2][0], rc[2][1], rc[2][2], rc[2][3]);
    *(uint2*)&rp[48] = pk4bf(rc[3][0], rc[3][1], rc[3][2], rc[3][3]);
    if (lq == 0) Rx[slot * 68 + 64] = (unsigned short)f2bfu(rc[4][0]);
  };

  // ---- prefill Rx with ai in [-i0, -i0+127] (disjoint slots) ----
  {
    u4bf b0, b1;
    loadBe(-i0, b0, b1);
    rslabCompute(-i0, b0, b1);
    loadBe(-i0 + 64, b0, b1);
    rslabCompute(-i0 + 64, b0, b1);
  }
  // prefetch Er B-fragments for tb=1 (A0 = -i0+127)
  u4bf pb0, pb1;
  loadBe(-i0 + 127, pb0, pb1);

  f32x4 O[5];  // O[4] = row-sum l accumulator
#pragma unroll
  for (int a = 0; a < 5; ++a) O[a] = (f32x4){0.f, 0.f, 0.f, 0.f};

  for (int tb = 0; tb < 32; ++tb) {
    const int t0 = tb * 64, dbase = t0 - i0;
    __syncthreads();  // (a) prior-iter consumers (QK/PV/gather) done

    stageTile(kbase + (size_t)t0 * 512, 512, Ks);
    stageTile(vtb + t0, 2048, VTs);
    if (tb > 0) {
      rslabCompute(dbase + 63, pb0, pb1);
      if (tb < 31) loadBe(dbase + 127, pb0, pb1);  // prefetch next iter
    }
    __syncthreads();  // (b) staging DMA drained + Rx visible

    // ---- QK^T (swapped) + gather + exp, per nt; builds PV A-frag words ----
    unsigned afw[8];
    __builtin_amdgcn_s_setprio(1);
#pragma unroll
    for (int nt = 0; nt < 4; ++nt) {
      int rb = (nt * 16 + lm) * 64;
      u4bf bk0, bk1;
      bk0.u = *(const uint4*)&Ks[rb + ko0];
      bk1.u = *(const uint4*)&Ks[rb + ko1];
      // rel reads are sc-independent: issue before MFMA consumes bk
      float rel[4];
#pragma unroll
      for (int reg = 0; reg < 4; ++reg) {
        int ai = dbase + cnn + nt * 16 + reg;
        rel[reg] = bf2f(Rx[(ai & 127) * 68 + iselb + (ai >= 65 ? 1 : 0)]);
      }
      f32x4 sc = (f32x4){0.f, 0.f, 0.f, 0.f};
      sc = MFMA16(bk0.v, aqw[0].v, sc);   // A=K rows (t), B=Q rows (i)
      sc = MFMA16(bk1.v, aqw[1].v, sc);
      float pv0 = fast_exp2(sc[0] + rel[0]);
      float pv1 = fast_exp2(sc[1] + rel[1]);
      float pv2 = fast_exp2(sc[2] + rel[2]);
      float pv3 = fast_exp2(sc[3] + rel[3]);
      uint2 pp = pk4bf(pv0, pv1, pv2, pv3);
      afw[nt * 2] = pp.x;
      afw[nt * 2 + 1] = pp.y;
    }
    __builtin_amdgcn_s_setprio(0);

    u4bf af0, af1;
    af0.u = make_uint4(afw[0], afw[1], afw[2], afw[3]);  // ka=0: t 0..31
    af1.u = make_uint4(afw[4], afw[5], afw[6], afw[7]);  // ka=1: t 32..63

    // ---- PV + l (A-frag straight from registers) ----
    __builtin_amdgcn_s_setprio(1);
#pragma unroll
    for (int ka = 0; ka < 2; ++ka) {
      u4bf ap = (ka == 0) ? af0 : af1;
#pragma unroll
      for (int nt = 0; nt < 4; ++nt) {
        int rb = (nt * 16 + lm) * 64;
        u4bf bv;
        bv.u = *(const uint4*)&VTs[rb + (ka == 0 ? ko0 : ko1)];
        O[nt] = MFMA16(ap.v, bv.v, O[nt]);
      }
      O[4] = MFMA16(ap.v, ones.v, O[4]);
    }
    __builtin_amdgcn_s_setprio(0);
  }

  // epilogue: every lane holds l in O[4][reg]
  float* ob = out + ((size_t)(b * 2048) + i0) * 512 + h * 64;
#pragma unroll
  for (int reg = 0; reg < 4; ++reg) {
    float inv = 1.f / O[4][reg];
#pragma unroll
    for (int nt = 0; nt < 4; ++nt)
      ob[(size_t)il_[reg] * 512 + nt * 16 + lm] = O[nt][reg] * inv;
  }

  // ---- R15: fused LayerNorm, last-block-per-(b,qp) completion ----
  __threadfence();  // release: our out-writes visible device-wide
  if (tid == 0) {
    int old = atomicAdd(&cnt[b * 32 + qp], 1);
    isLast = (old == 7);
  }
  __syncthreads();
  if (isLast) {
    __threadfence();  // acquire: invalidate stale cached lines
    float* rowbase = out + ((size_t)(b * 2048) + i0) * 512;
    float4 g0 = *(const float4*)&gamma[l * 8];
    float4 g1 = *(const float4*)&gamma[l * 8 + 4];
    float4 b0 = *(const float4*)&beta[l * 8];
    float4 b1 = *(const float4*)&beta[l * 8 + 4];
    for (int k = 0; k < 16; ++k) {
      int r = k * 4 + w;  // wave w owns rows w, w+4, ..., w+60
      float* xr = rowbase + (size_t)r * 512 + l * 8;
      float4 a = *(const float4*)xr;
      float4 c = *(const float4*)(xr + 4);
      float s = a.x + a.y + a.z + a.w + c.x + c.y + c.z + c.w;
      float sq = a.x * a.x + a.y * a.y + a.z * a.z + a.w * a.w +
                 c.x * c.x + c.y * c.y + c.z * c.z + c.w * c.w;
#pragma unroll
      for (int off = 1; off < 64; off <<= 1) {
        s += __shfl_xor(s, off, 64);
        sq += __shfl_xor(sq, off, 64);
      }
      const float mean = s * (1.f / 512.f);
      float var = sq * (1.f / 512.f) - mean * mean;
      var = fmaxf(var, 0.f);
      const float rstd = rsqrtf(var + 1e-5f);
      float4 oA, oC;
      oA.x = (a.x - mean) * rstd * g0.x + b0.x;
      oA.y = (a.y - mean) * rstd * g0.y + b0.y;
      oA.z = (a.z - mean) * rstd * g0.z + b0.z;
      oA.w = (a.w - mean) * rstd * g0.w + b0.w;
      oC.x = (c.x - mean) * rstd * g1.x + b1.x;
      oC.y = (c.y - mean) * rstd * g1.y + b1.y;
      oC.z = (c.z - mean) * rstd * g1.z + b1.z;
      oC.w = (c.w - mean) * rstd * g1.w + b1.w;
      *(float4*)xr = oA;
      *(float4*)(xr + 4) = oC;
    }
  }
}

extern "C" void kernel_launch(void* const* d_in, const int* in_sizes, int n_in,
                              void* d_out, int out_size, void* d_ws, size_t ws_size,
                              hipStream_t stream) {
  const float* x     = (const float*)d_in[0];
  const float* Wq    = (const float*)d_in[1];
  const float* Wk    = (const float*)d_in[2];
  const float* Wv    = (const float*)d_in[3];
  const float* Er    = (const float*)d_in[4];
  const float* gamma = (const float*)d_in[5];
  const float* beta  = (const float*)d_in[6];
  float* out = (float*)d_out;

  // ws layout (bf16 shorts): qkv 3*8192*512 (z=2 region unused) |
  //   vT 4*512*2048 | erb 2049*64 | xb 8192*512 | wb 3*512*512 | cnt 128 int
  unsigned short* qkvb = (unsigned short*)d_ws;
  unsigned short* vtb  = qkvb + (size_t)3 * 8192 * 512;
  unsigned short* erb  = vtb + (size_t)4 * 512 * 2048;
  unsigned short* xb   = erb + (size_t)2049 * 64;
  unsigned short* wb   = xb + (size_t)8192 * 512;
  int* cnt             = (int*)(wb + (size_t)3 * 512 * 512);

  conv_all<<<dim3(2497), 256, 0, stream>>>(x, Wq, Wk, Wv, Er, xb, wb, erb, cnt);
  qkv_gemm_mfma<<<dim3(64, 4, 3), 256, 0, stream>>>(xb, wb, qkvb, vtb);
  attn_mfma<<<dim3(32, 32), 256, 0, stream>>>(qkvb, qkvb + (size_t)8192 * 512, vtb, erb,
                                              out, cnt, gamma, beta);
}

// Round 10
// 207.944 us; speedup vs baseline: 1.6275x; 1.6275x over previous
//
#include <hip/hip_runtime.h>

#define B_ 4
#define S_ 2048
#define E_ 512
#define H_ 8
#define HD_ 64

typedef float f32x4 __attribute__((ext_vector_type(4)));
typedef __bf16 bf16x8 __attribute__((ext_vector_type(8)));

#define MFMA16(a, b, c) __builtin_amdgcn_mfma_f32_16x16x32_bf16((a), (b), (c), 0, 0, 0)

__device__ __forceinline__ unsigned f2bfu(float f) {
  union { float f; unsigned u; } x; x.f = f;
  return (x.u + 0x8000u) >> 16;
}
__device__ __forceinline__ unsigned pk2bf(float lo, float hi) {
  union { float f; unsigned u; } a, b; a.f = lo; b.f = hi;
  return ((b.u + 0x8000u) & 0xFFFF0000u) | ((a.u + 0x8000u) >> 16);
}
// 4x f32 -> 4x bf16 (RNE) packed in uint2; compiler emits v_cvt_pk_bf16_f32.
__device__ __forceinline__ uint2 pk4bf(float a, float b, float c, float d) {
  union { __bf16 h[4]; uint2 q; } u;
  u.h[0] = (__bf16)a; u.h[1] = (__bf16)b; u.h[2] = (__bf16)c; u.h[3] = (__bf16)d;
  return u.q;
}
__device__ __forceinline__ float bf2f(unsigned short s) {
  union { unsigned u; float f; } x; x.u = ((unsigned)s) << 16;
  return x.f;
}
__device__ __forceinline__ float fast_exp2(float x) {
  float r;
  __asm__("v_exp_f32 %0, %1" : "=v"(r) : "v"(x));
  return r;
}
// async global->LDS, 16B per lane. LDS dest = wave-uniform base + lane*16.
__device__ __forceinline__ void gload_lds16(const unsigned short* g, unsigned short* l) {
  __builtin_amdgcn_global_load_lds(
      (const __attribute__((address_space(1))) unsigned int*)g,
      (__attribute__((address_space(3))) unsigned int*)l, 16, 0, 0);
}

// ---------------------------------------------------------------------------
// Fused input conversion. blocks 0..2047: x -> xb (bf16).
// blocks 2048..2431: W (128/matrix); 2432..2495: Er (d-permuted); 2496: zero row.
// ---------------------------------------------------------------------------
__global__ __launch_bounds__(256) void conv_all(
    const float* __restrict__ x, const float* __restrict__ Wq,
    const float* __restrict__ Wk, const float* __restrict__ Wv,
    const float* __restrict__ Er, unsigned short* __restrict__ xb,
    unsigned short* __restrict__ wb, unsigned short* __restrict__ erb)
{
  const int bid = blockIdx.x, tid = threadIdx.x;
  if (bid < 2048) {
    size_t i = ((size_t)bid * 256 + tid) * 8;
    float4 f0 = *(const float4*)&x[i];
    float4 f1 = *(const float4*)&x[i + 4];
    uint4 o;
    o.x = pk2bf(f0.x, f0.y); o.y = pk2bf(f0.z, f0.w);
    o.z = pk2bf(f1.x, f1.y); o.w = pk2bf(f1.z, f1.w);
    *(uint4*)&xb[i] = o;
  } else if (bid < 2432) {
    int wz = bid - 2048;
    int z = wz >> 7, mi = wz & 127;
    const float* src = (z == 0) ? Wq : (z == 1) ? Wk : Wv;
    size_t off = (size_t)mi * 2048 + tid * 8;
    float4 f0 = *(const float4*)&src[off];
    float4 f1 = *(const float4*)&src[off + 4];
    uint4 o;
    o.x = pk2bf(f0.x, f0.y); o.y = pk2bf(f0.z, f0.w);
    o.z = pk2bf(f1.x, f1.y); o.w = pk2bf(f1.z, f1.w);
    *(uint4*)&wb[(size_t)z * 262144 + off] = o;
  } else if (bid < 2496) {
    size_t off = (size_t)(bid - 2432) * 2048 + tid * 8;
    int row = (int)(off >> 6), d0 = (int)(off & 63);
    float4 f0 = *(const float4*)&Er[off];
    float4 f1 = *(const float4*)&Er[off + 4];
    float vals[8] = {f0.x, f0.y, f0.z, f0.w, f1.x, f1.y, f1.z, f1.w};
#pragma unroll
    for (int j = 0; j < 8; ++j) {
      int d = d0 + j;
      int dp = (d & 15) * 4 + (d >> 4);
      erb[(size_t)row * 64 + dp] = (unsigned short)f2bfu(vals[j]);
    }
  } else {
    if (tid < 8) *(uint4*)&erb[2048 * 64 + tid * 8] = make_uint4(0, 0, 0, 0);
  }
}

// ---------------------------------------------------------------------------
// QKV projection, pure-bf16 MFMA with global_load_lds staging.
// z in {0,1}: out[z] = bf16(xb @ wb[z]^T) to qkvb, d-axis permuted within
//   64-blocks (d' = (d&15)*4 + d>>4), Q pre-scaled by 512^-0.5 * log2(e).
// z == 2: fused V transpose epilogue writes vtb directly in attn's
//   [d][t-perm] layout (t(p) = (p&32)+((p>>2)&1)*16+((p>>3)&3)*4+(p&3)).
// R16: XCD-grouping remap (bijective, 768 = 8x96): all 12 (y,z) consumers
//   of each A-row-tile land on ONE XCD -> xb panels L2-resident (1MB/XCD),
//   no cross-XCD A re-fetch. Work mapping only; correctness-neutral.
// M=8192,N=512,K=512. grid (64,4,3), 256 thr.
// ---------------------------------------------------------------------------
__global__ __launch_bounds__(256) void qkv_gemm_mfma(
    const unsigned short* __restrict__ xb, const unsigned short* __restrict__ wb,
    unsigned short* __restrict__ qkvb, unsigned short* __restrict__ vtb)
{
  // ---- XCD grouping: hw round-robins linear id % 8 across XCDs ----
  const int Lf = blockIdx.x + blockIdx.y * 64 + blockIdx.z * 256;  // 0..767
  const int nf = (Lf & 7) * 96 + (Lf >> 3);                        // bijective
  const int mi = nf / 12, r = nf % 12;
  const int z = r >> 2, yb = r & 3;
  const unsigned short* W = wb + (size_t)z * 262144;
  const int m0 = mi * 128, n0 = yb * 128;

  // 34816B: As (16KB) | Bs (16KB) during K-loop; Tt 4x64x68 in epilogue (z==2)
  __shared__ __align__(16) unsigned short SMEM[17408];
  unsigned short* As = SMEM;
  unsigned short* Bs = SMEM + 8192;

  const int tid = threadIdx.x;
  const int w = tid >> 6, l = tid & 63, lm = l & 15, lq = l >> 4;
  const int wm = w & 1, wn = w >> 1;

  union u4bf { uint4 u; bf16x8 v; };
  f32x4 acc[4][4];
#pragma unroll
  for (int a = 0; a < 4; ++a)
#pragma unroll
    for (int b = 0; b < 4; ++b) acc[a][b] = (f32x4){0.f, 0.f, 0.f, 0.f};

  for (int k0 = 0; k0 < 512; k0 += 64) {
    const unsigned short* xa = xb + (size_t)m0 * 512 + k0;
    const unsigned short* wz = W + (size_t)n0 * 512 + k0;
    __syncthreads();
#pragma unroll
    for (int rr = 0; rr < 4; ++rr) {
      int cb = rr * 256 + w * 64;
      int s = cb + l;
      int row = s >> 3, c = (s & 7) ^ (row & 7);
      gload_lds16(&xa[(size_t)row * 512 + c * 8], &As[cb * 8]);
      gload_lds16(&wz[(size_t)row * 512 + c * 8], &Bs[cb * 8]);
    }
    __syncthreads();
#pragma unroll
    for (int ka = 0; ka < 2; ++ka) {
      u4bf af[4];
#pragma unroll
      for (int mt = 0; mt < 4; ++mt) {
        int row = wm * 64 + mt * 16 + lm;
        af[mt].u = *(const uint4*)&As[row * 64 + (((ka * 4 + lq) ^ (row & 7)) * 8)];
      }
#pragma unroll
      for (int nt = 0; nt < 4; ++nt) {
        int row = wn * 64 + nt * 16 + lm;
        u4bf bfv;
        bfv.u = *(const uint4*)&Bs[row * 64 + (((ka * 4 + lq) ^ (row & 7)) * 8)];
#pragma unroll
        for (int mt = 0; mt < 4; ++mt) acc[mt][nt] = MFMA16(af[mt].v, bfv.v, acc[mt][nt]);
      }
    }
  }

  if (z != 2) {
    const float m = (z == 0) ? 0.06376695f : 1.0f;  // 512^-0.5 * log2(e) for Q
    unsigned short* out = qkvb + (size_t)z * (8192u * 512u);
#pragma unroll
    for (int mt = 0; mt < 4; ++mt)
#pragma unroll
      for (int reg = 0; reg < 4; ++reg) {
        int row = m0 + wm * 64 + mt * 16 + lq * 4 + reg;
        uint2 v = make_uint2(
            pk2bf(acc[mt][0][reg] * m, acc[mt][1][reg] * m),
            pk2bf(acc[mt][2][reg] * m, acc[mt][3][reg] * m));
        *(uint2*)&out[(size_t)row * 512 + n0 + wn * 64 + lm * 4] = v;
      }
  } else {
    // ---- fused V transpose: wave (wm,wn) owns the 64t x 64d subtile ----
    __syncthreads();  // all waves done with As/Bs before aliasing
    unsigned short* R = SMEM + w * 4352;  // 64 x 68 wave-private
#pragma unroll
    for (int mt = 0; mt < 4; ++mt)
#pragma unroll
      for (int nt = 0; nt < 4; ++nt)
#pragma unroll
        for (int reg = 0; reg < 4; ++reg)
          R[(mt * 16 + lq * 4 + reg) * 68 + nt * 16 + lm] =
              (unsigned short)f2bfu(acc[mt][nt][reg]);
    __asm__ __volatile__("" ::: "memory");  // same-wave DS RAW (in-order pipe)
    const int sg0 = m0 + wm * 64;           // global s of this chunk
    const int bb = sg0 >> 11, sl = sg0 & 2047;
    const int db64 = yb * 2 + wn;           // 64-wide d block index
#pragma unroll
    for (int it = 0; it < 8; ++it) {
      int j = it * 64 + l;
      int dp = j >> 3, s8 = (j & 7) * 8;
      union { unsigned short u[8]; uint4 q; } tmp;
#pragma unroll
      for (int jj = 0; jj < 8; ++jj) {
        int p = s8 + jj;
        int ts = (p & 32) + (((p >> 2) & 1) << 4) + (((p >> 3) & 3) << 2) + (p & 3);
        tmp.u[jj] = R[ts * 68 + dp];
      }
      *(uint4*)&vtb[((size_t)(bb * 512) + db64 * 64 + dp) * 2048 + sl + s8] = tmp.q;
    }
  }
}

// ---------------------------------------------------------------------------
// Fused attention — R16: exact R13 body (best measured: 113.4us).
// R14 (address-free gather) and R15 (LN fusion w/ threadfence) both
// regressed and are reverted; ledger says only structural deletions on the
// critical path win here. Swapped QK (sc = mfma(K,Q)) puts each lane's
// P-row in registers; PV A-frag = 2x pk4bf of the exp outputs; V^T arrives
// from qkv's fused epilogue in [d][t-perm] layout.
// Kept: XCD bijective remap, setprio, 2 barriers/iter, Rx[slot][isel] s68.
// grid (32,32)=1024 = exactly 4 blocks/CU (LDS 33.8K), 256 thr.
// ---------------------------------------------------------------------------
__global__ __launch_bounds__(256, 4) void attn_mfma(
    const unsigned short* __restrict__ qw, const unsigned short* __restrict__ kw,
    const unsigned short* __restrict__ vt, const unsigned short* __restrict__ erb,
    float* __restrict__ out)
{
  // ---- XCD-aware bijective remap (hw round-robins linear id % 8) ----
  const int Lf = blockIdx.y * 32 + blockIdx.x;
  const int nf = (Lf & 7) * 128 + (Lf >> 3);
  const int qp = nf & 31, bh = nf >> 5;
  const int b = bh >> 3, h = bh & 7;
  const int i0 = qp * 64;

  __shared__ __align__(16) unsigned short Ks[64 * 64];   // [t][d'] swizzled
  __shared__ __align__(16) unsigned short VTs[64 * 64];  // [d][t-perm] swizzled
  __shared__ __align__(16) unsigned short Rx[128 * 68];  // [slot][isel]

  const int tid = threadIdx.x;
  const int w = tid >> 6, l = tid & 63, lm = l & 15, lq = l >> 4;

  const unsigned short* qbase = qw + ((size_t)(b * 2048)) * 512 + h * 64;
  const unsigned short* kbase = kw + ((size_t)(b * 2048)) * 512 + h * 64;
  const unsigned short* vtb = vt + ((size_t)(b * 512 + h * 64)) * 2048;

  union u4bf { uint4 u; bf16x8 v; };

  u4bf ones;
  ones.u = make_uint4(0x3F803F80u, 0x3F803F80u, 0x3F803F80u, 0x3F803F80u);

  // ---- loop-invariant constants ----
  const int ko0 = (lq ^ (lm & 7)) * 8;        // swizzled frag offset, ka=0
  const int ko1 = ((4 + lq) ^ (lm & 7)) * 8;  // ka=1
  const int cnn = 63 + lq * 4 - (w * 16 + lm);  // ai = dbase + cnn + nt*16 + reg
  const int iselb = w * 16 + lm;                // gather column base (own i)
  int il_[4];
#pragma unroll
  for (int reg = 0; reg < 4; ++reg) il_[reg] = w * 16 + lq * 4 + reg;

  // ---- wave's own Q fragment (B-operand of swapped QK) ----
  u4bf aqw[2];
  {
    int gi = i0 + w * 16 + lm;
    aqw[0].u = *(const uint4*)&qbase[(size_t)gi * 512 + lq * 8];
    aqw[1].u = *(const uint4*)&qbase[(size_t)gi * 512 + 32 + lq * 8];
  }
  // ---- Q-ext fragments for rslab (rows rt*16+lm; >64 or OOB -> 0),
  //      constant-indexed ONLY (R2 lesson) ----
  u4bf aq[5][2];
#pragma unroll
  for (int rt = 0; rt < 5; ++rt) {
    int row = rt * 16 + lm, gi = i0 + row;
#pragma unroll
    for (int ka = 0; ka < 2; ++ka) {
      if (row <= 64 && gi < 2048)
        aq[rt][ka].u = *(const uint4*)&qbase[(size_t)gi * 512 + ka * 32 + lq * 8];
      else
        aq[rt][ka].u = make_uint4(0, 0, 0, 0);
    }
  }

  // 4 waves stage a 64x64 tile: two gload_lds16 per wave.
  auto stageTile = [&](const unsigned short* srcBase, size_t srcStride,
                       unsigned short* dst) {
#pragma unroll
    for (int rr = 0; rr < 2; ++rr) {
      int cb = rr * 256 + w * 64;
      int s = cb + l;
      int row = s >> 3, c = (s & 7) ^ (row & 7);
      gload_lds16(&srcBase[(size_t)row * srcStride + c * 8], &dst[cb * 8]);
    }
  };
  auto loadBe = [&](int A0, u4bf& be0, u4bf& be1) {
    int ai = A0 + w * 16 + lm;
    int g = (ai < 64) ? (1984 + ai) : (ai == 64 ? 2048 : ai - 65);
    const unsigned short* ep = &erb[(size_t)g * 64];
    be0.u = *(const uint4*)&ep[lq * 8];
    be1.u = *(const uint4*)&ep[32 + lq * 8];
  };
  auto rslabCompute = [&](int A0, u4bf be0, u4bf be1) {
    f32x4 rc[5];
#pragma unroll
    for (int rt = 0; rt < 5; ++rt) rc[rt] = (f32x4){0.f, 0.f, 0.f, 0.f};
    rc[0] = MFMA16(aq[0][0].v, be0.v, rc[0]);
    rc[0] = MFMA16(aq[0][1].v, be1.v, rc[0]);
    rc[1] = MFMA16(aq[1][0].v, be0.v, rc[1]);
    rc[1] = MFMA16(aq[1][1].v, be1.v, rc[1]);
    rc[2] = MFMA16(aq[2][0].v, be0.v, rc[2]);
    rc[2] = MFMA16(aq[2][1].v, be1.v, rc[2]);
    rc[3] = MFMA16(aq[3][0].v, be0.v, rc[3]);
    rc[3] = MFMA16(aq[3][1].v, be1.v, rc[3]);
    rc[4] = MFMA16(aq[4][0].v, be0.v, rc[4]);
    rc[4] = MFMA16(aq[4][1].v, be1.v, rc[4]);
    int slot = (A0 + w * 16 + lm) & 127;
    unsigned short* rp = &Rx[slot * 68 + lq * 4];
    *(uint2*)&rp[0]  = pk4bf(rc[0][0], rc[0][1], rc[0][2], rc[0][3]);
    *(uint2*)&rp[16] = pk4bf(rc[1][0], rc[1][1], rc[1][2], rc[1][3]);
    *(uint2*)&rp[32] = pk4bf(rc[2][0], rc[2][1], rc[2][2], rc[2][3]);
    *(uint2*)&rp[48] = pk4bf(rc[3][0], rc[3][1], rc[3][2], rc[3][3]);
    if (lq == 0) Rx[slot * 68 + 64] = (unsigned short)f2bfu(rc[4][0]);
  };

  // ---- prefill Rx with ai in [-i0, -i0+127] (disjoint slots) ----
  {
    u4bf b0, b1;
    loadBe(-i0, b0, b1);
    rslabCompute(-i0, b0, b1);
    loadBe(-i0 + 64, b0, b1);
    rslabCompute(-i0 + 64, b0, b1);
  }
  // prefetch Er B-fragments for tb=1 (A0 = -i0+127)
  u4bf pb0, pb1;
  loadBe(-i0 + 127, pb0, pb1);

  f32x4 O[5];  // O[4] = row-sum l accumulator
#pragma unroll
  for (int a = 0; a < 5; ++a) O[a] = (f32x4){0.f, 0.f, 0.f, 0.f};

  for (int tb = 0; tb < 32; ++tb) {
    const int t0 = tb * 64, dbase = t0 - i0;
    __syncthreads();  // (a) prior-iter consumers (QK/PV/gather) done

    stageTile(kbase + (size_t)t0 * 512, 512, Ks);
    stageTile(vtb + t0, 2048, VTs);
    if (tb > 0) {
      rslabCompute(dbase + 63, pb0, pb1);
      if (tb < 31) loadBe(dbase + 127, pb0, pb1);  // prefetch next iter
    }
    __syncthreads();  // (b) staging DMA drained + Rx visible

    // ---- QK^T (swapped) + gather + exp, per nt; builds PV A-frag words ----
    unsigned afw[8];
    __builtin_amdgcn_s_setprio(1);
#pragma unroll
    for (int nt = 0; nt < 4; ++nt) {
      int rb = (nt * 16 + lm) * 64;
      u4bf bk0, bk1;
      bk0.u = *(const uint4*)&Ks[rb + ko0];
      bk1.u = *(const uint4*)&Ks[rb + ko1];
      // rel reads are sc-independent: issue before MFMA consumes bk
      float rel[4];
#pragma unroll
      for (int reg = 0; reg < 4; ++reg) {
        int ai = dbase + cnn + nt * 16 + reg;
        rel[reg] = bf2f(Rx[(ai & 127) * 68 + iselb + (ai >= 65 ? 1 : 0)]);
      }
      f32x4 sc = (f32x4){0.f, 0.f, 0.f, 0.f};
      sc = MFMA16(bk0.v, aqw[0].v, sc);   // A=K rows (t), B=Q rows (i)
      sc = MFMA16(bk1.v, aqw[1].v, sc);
      float pv0 = fast_exp2(sc[0] + rel[0]);
      float pv1 = fast_exp2(sc[1] + rel[1]);
      float pv2 = fast_exp2(sc[2] + rel[2]);
      float pv3 = fast_exp2(sc[3] + rel[3]);
      uint2 pp = pk4bf(pv0, pv1, pv2, pv3);
      afw[nt * 2] = pp.x;
      afw[nt * 2 + 1] = pp.y;
    }
    __builtin_amdgcn_s_setprio(0);

    u4bf af0, af1;
    af0.u = make_uint4(afw[0], afw[1], afw[2], afw[3]);  // ka=0: t 0..31
    af1.u = make_uint4(afw[4], afw[5], afw[6], afw[7]);  // ka=1: t 32..63

    // ---- PV + l (A-frag straight from registers) ----
    __builtin_amdgcn_s_setprio(1);
#pragma unroll
    for (int ka = 0; ka < 2; ++ka) {
      u4bf ap = (ka == 0) ? af0 : af1;
#pragma unroll
      for (int nt = 0; nt < 4; ++nt) {
        int rb = (nt * 16 + lm) * 64;
        u4bf bv;
        bv.u = *(const uint4*)&VTs[rb + (ka == 0 ? ko0 : ko1)];
        O[nt] = MFMA16(ap.v, bv.v, O[nt]);
      }
      O[4] = MFMA16(ap.v, ones.v, O[4]);
    }
    __builtin_amdgcn_s_setprio(0);
  }

  // epilogue: every lane holds l in O[4][reg]
  float* ob = out + ((size_t)(b * 2048) + i0) * 512 + h * 64;
#pragma unroll
  for (int reg = 0; reg < 4; ++reg) {
    float inv = 1.f / O[4][reg];
#pragma unroll
    for (int nt = 0; nt < 4; ++nt)
      ob[(size_t)il_[reg] * 512 + nt * 16 + lm] = O[nt][reg] * inv;
  }
}

// ---------------------------------------------------------------------------
// In-place LayerNorm over E=512 per (b,s) row.
// R16: one WAVE per row (8 floats/lane, pure shuffle reduction — no LDS,
// no __syncthreads). 4 rows/block, grid 2048.
// ---------------------------------------------------------------------------
__global__ __launch_bounds__(256) void ln_kernel(
    float* __restrict__ io, const float* __restrict__ gamma,
    const float* __restrict__ beta)
{
  const int tid = threadIdx.x;
  const int wv = tid >> 6, l = tid & 63;
  const int row = blockIdx.x * 4 + wv;
  float* xr = io + (size_t)row * 512 + l * 8;
  float4 a = *(const float4*)xr;
  float4 c = *(const float4*)(xr + 4);
  float s = a.x + a.y + a.z + a.w + c.x + c.y + c.z + c.w;
  float sq = a.x * a.x + a.y * a.y + a.z * a.z + a.w * a.w +
             c.x * c.x + c.y * c.y + c.z * c.z + c.w * c.w;
#pragma unroll
  for (int off = 1; off < 64; off <<= 1) {
    s += __shfl_xor(s, off, 64);
    sq += __shfl_xor(sq, off, 64);
  }
  const float mean = s * (1.f / 512.f);
  float var = sq * (1.f / 512.f) - mean * mean;
  var = fmaxf(var, 0.f);
  const float rstd = rsqrtf(var + 1e-5f);
  float4 g0 = *(const float4*)&gamma[l * 8];
  float4 g1 = *(const float4*)&gamma[l * 8 + 4];
  float4 b0 = *(const float4*)&beta[l * 8];
  float4 b1 = *(const float4*)&beta[l * 8 + 4];
  float4 oA, oC;
  oA.x = (a.x - mean) * rstd * g0.x + b0.x;
  oA.y = (a.y - mean) * rstd * g0.y + b0.y;
  oA.z = (a.z - mean) * rstd * g0.z + b0.z;
  oA.w = (a.w - mean) * rstd * g0.w + b0.w;
  oC.x = (c.x - mean) * rstd * g1.x + b1.x;
  oC.y = (c.y - mean) * rstd * g1.y + b1.y;
  oC.z = (c.z - mean) * rstd * g1.z + b1.z;
  oC.w = (c.w - mean) * rstd * g1.w + b1.w;
  *(float4*)xr = oA;
  *(float4*)(xr + 4) = oC;
}

extern "C" void kernel_launch(void* const* d_in, const int* in_sizes, int n_in,
                              void* d_out, int out_size, void* d_ws, size_t ws_size,
                              hipStream_t stream) {
  const float* x     = (const float*)d_in[0];
  const float* Wq    = (const float*)d_in[1];
  const float* Wk    = (const float*)d_in[2];
  const float* Wv    = (const float*)d_in[3];
  const float* Er    = (const float*)d_in[4];
  const float* gamma = (const float*)d_in[5];
  const float* beta  = (const float*)d_in[6];
  float* out = (float*)d_out;

  // ws layout (bf16 shorts): qkv 3*8192*512 (z=2 region unused) |
  //   vT 4*512*2048 | erb 2049*64 | xb 8192*512 | wb 3*512*512  (~41.8 MB)
  unsigned short* qkvb = (unsigned short*)d_ws;
  unsigned short* vtb  = qkvb + (size_t)3 * 8192 * 512;
  unsigned short* erb  = vtb + (size_t)4 * 512 * 2048;
  unsigned short* xb   = erb + (size_t)2049 * 64;
  unsigned short* wb   = xb + (size_t)8192 * 512;

  conv_all<<<dim3(2497), 256, 0, stream>>>(x, Wq, Wk, Wv, Er, xb, wb, erb);
  qkv_gemm_mfma<<<dim3(64, 4, 3), 256, 0, stream>>>(xb, wb, qkvb, vtb);
  attn_mfma<<<dim3(32, 32), 256, 0, stream>>>(qkvb, qkvb + (size_t)8192 * 512, vtb, erb, out);
  ln_kernel<<<dim3(2048), 256, 0, stream>>>(out, gamma, beta);
}